// Round 8
// baseline (32.542 us; speedup 1.0000x reference)
//
#include <hip/hip_runtime.h>
#include <math.h>

#define N_  2
#define A_  360
#define M_  512
#define NP_ 32
#define PS_ 64
#define TEAM_A  180
#define TA_ANG  88            // per-team angles gathered direct from global (22 groups)
#define LDS_ANG 92            // per-team angles gathered from LDS windows (23 groups)
#define NW      (2 * LDS_ANG) // 184 staged windows
#define W_      24            // float2 pairs per window (region span <=21.3, +interp)

// unaligned-tolerant float2 for the global-gather path (4B-aligned addresses)
typedef float f2u __attribute__((ext_vector_type(2), aligned(4)));

// 512-thread blocks, two 256-thread angle-teams per 16x16 pixel region.
// Gathers are split across the two independent memory pipes:
//   - 88 angles/team: direct global gather (TA pipe, sino is L1/L2-resident)
//   - 92 angles/team: LDS pair-windows, one aligned ds_read_b64 per gather
// interleaved 4+4 per loop group so TA (vmcnt) and LDS (lgkmcnt) overlap.
__global__ __launch_bounds__(512) void fbp_kernel(
    const float* __restrict__ sino,   // (N,1,A,M)
    const float* __restrict__ theta,  // (A)
    const float* __restrict__ cxs,    // (NP)
    const float* __restrict__ cys,    // (NP)
    float* __restrict__ out)          // (N,NP,PS,PS)
{
    __shared__ float2 win2[NW * W_];               // 35328 B: {s[k], s[k+1]} pairs
    __shared__ alignas(16) float csA[A_];          // 1440 B: cos*half
    __shared__ alignas(16) float syA[A_];          // 1440 B: sin*half
    __shared__ alignas(16) float ofA[NW];          //  736 B: half - lo (window angles)
    __shared__ float red[256];                     // 1024 B  => 39968 B -> 4 blocks/CU

    const float half = 255.5f;        // (M-1)/2
    const int tid = threadIdx.x;

    const int bid    = blockIdx.x;
    const int region = bid & 15;            // 4x4 regions per 64x64 patch
    const int p      = (bid >> 4) & (NP_ - 1);
    const int n      = bid >> 9;
    const int ri     = (region >> 2) << 4;
    const int rj     = (region &  3) << 4;

    const float cx = cxs[p];
    const float cy = cys[p];

    // Region corner coords (same op sequence as per-pixel => covering bounds)
    const float gX0 = ((float)(ri      - PS_ / 2) + cx) / half - 1.0f;
    const float gX1 = ((float)(ri + 15 - PS_ / 2) + cx) / half - 1.0f;
    const float gy0 = ((float)(rj      - PS_ / 2) + cy) / half - 1.0f;
    const float gy1 = ((float)(rj + 15 - PS_ / 2) + cy) / half - 1.0f;

    // Phase A: per-angle trig; window origin for the LDS-gathered angles
    if (tid < A_) {
        const float th  = theta[tid];
        const float csx = cosf(th) * half;
        const float csy = sinf(th) * half;
        csA[tid] = csx;
        syA[tid] = csy;
        const int tm = (tid >= TEAM_A) ? 1 : 0;
        const int al = tid - tm * TEAM_A;
        if (al >= TA_ANG) {
            const float t0  = fmaf(-gy0, csy, half);
            const float t1  = fmaf(-gy1, csy, half);
            const float u00 = fmaf(gX0, csx, t0);
            const float u10 = fmaf(gX1, csx, t0);
            const float u01 = fmaf(gX0, csx, t1);
            const float u11 = fmaf(gX1, csx, t1);
            const float lof = floorf(fminf(fminf(u00, u10), fminf(u01, u11)));
            ofA[tm * LDS_ANG + (al - TA_ANG)] = half - lof;   // exact
        }
    }
    __syncthreads();

    // Phase B: stage pair-windows (coalesced global reads, linear LDS writes)
    const float* __restrict__ srow = sino + n * (A_ * M_);
    for (int e = tid; e < NW * W_; e += 512) {
        const int w  = e / W_;
        const int k  = e - w * W_;
        const int a  = (w < LDS_ANG) ? (w + TA_ANG) : (w + TA_ANG + TA_ANG);
        const int lo = (int)(half - ofA[w]);
        const int i0 = min(max(lo + k,     0), M_ - 1);
        const int i1 = min(max(lo + k + 1, 0), M_ - 1);
        win2[e] = make_float2(srow[a * M_ + i0], srow[a * M_ + i1]);
    }
    __syncthreads();

    // Phase C: 180 angles per team, gathers split TA / LDS
    const int team = tid >> 8;
    const int t    = tid & 255;
    const int i    = ri + (t >> 4);
    const int j    = rj + (t & 15);

    const float gX  = ((float)(i - PS_ / 2) + cx) / half - 1.0f;
    const float gy  = ((float)(j - PS_ / 2) + cy) / half - 1.0f;
    const float ngy = -gy;

    const float4* __restrict__ cs4 = (const float4*)csA;
    const float4* __restrict__ sy4 = (const float4*)syA;
    const float4* __restrict__ of4 = (const float4*)ofA;

    const int cs_base  = team * 45;        // float4 groups: team's angle 0
    const int csl_base = team * 45 + 22;   // float4 groups: team's angle 88
    const int of_base  = team * 23;
    const float*  __restrict__ srowTA = srow + team * TEAM_A * M_;
    const float2* __restrict__ wbase  = win2 + team * LDS_ANG * W_;

    float accG = 0.0f;
    float accW = 0.0f;

    #pragma unroll 2
    for (int q = 0; q < 22; ++q) {
        // ---- TA group: 4 global gathers (issue early) ----
        const float4 c4 = cs4[cs_base + q];
        const float4 s4 = sy4[cs_base + q];
        const float* r  = srowTA + (q * 4) * M_;

        float u0 = fmaf(gX, c4.x, fmaf(ngy, s4.x, half));
        float u1 = fmaf(gX, c4.y, fmaf(ngy, s4.y, half));
        float u2 = fmaf(gX, c4.z, fmaf(ngy, s4.z, half));
        float u3 = fmaf(gX, c4.w, fmaf(ngy, s4.w, half));
        u0 = fminf(fmaxf(u0, 0.0f), 510.999f);
        u1 = fminf(fmaxf(u1, 0.0f), 510.999f);
        u2 = fminf(fmaxf(u2, 0.0f), 510.999f);
        u3 = fminf(fmaxf(u3, 0.0f), 510.999f);
        const f2u ga0 = *(const f2u*)(r + 0 * M_ + (int)u0);
        const f2u ga1 = *(const f2u*)(r + 1 * M_ + (int)u1);
        const f2u ga2 = *(const f2u*)(r + 2 * M_ + (int)u2);
        const f2u ga3 = *(const f2u*)(r + 3 * M_ + (int)u3);
        const float wa0 = __builtin_amdgcn_fractf(u0);
        const float wa1 = __builtin_amdgcn_fractf(u1);
        const float wa2 = __builtin_amdgcn_fractf(u2);
        const float wa3 = __builtin_amdgcn_fractf(u3);

        // ---- LDS group: 4 window gathers (run while TA loads fly) ----
        const float4 cl = cs4[csl_base + q];
        const float4 sl = sy4[csl_base + q];
        const float4 o4 = of4[of_base + q];
        const float2* wp = wbase + (q * 4) * W_;
        {
            float u = fmaf(gX, cl.x, fmaf(ngy, sl.x, o4.x));
            u = fminf(fmaxf(u, 0.0f), 22.999f);
            const float2 g = wp[(int)u];
            accG += g.x;  accW = fmaf(__builtin_amdgcn_fractf(u), g.y - g.x, accW);
        }
        {
            float u = fmaf(gX, cl.y, fmaf(ngy, sl.y, o4.y));
            u = fminf(fmaxf(u, 0.0f), 22.999f);
            const float2 g = wp[W_ + (int)u];
            accG += g.x;  accW = fmaf(__builtin_amdgcn_fractf(u), g.y - g.x, accW);
        }
        {
            float u = fmaf(gX, cl.z, fmaf(ngy, sl.z, o4.z));
            u = fminf(fmaxf(u, 0.0f), 22.999f);
            const float2 g = wp[2 * W_ + (int)u];
            accG += g.x;  accW = fmaf(__builtin_amdgcn_fractf(u), g.y - g.x, accW);
        }
        {
            float u = fmaf(gX, cl.w, fmaf(ngy, sl.w, o4.w));
            u = fminf(fmaxf(u, 0.0f), 22.999f);
            const float2 g = wp[3 * W_ + (int)u];
            accG += g.x;  accW = fmaf(__builtin_amdgcn_fractf(u), g.y - g.x, accW);
        }

        // ---- consume TA results ----
        accG += ga0.x;  accW = fmaf(wa0, ga0.y - ga0.x, accW);
        accG += ga1.x;  accW = fmaf(wa1, ga1.y - ga1.x, accW);
        accG += ga2.x;  accW = fmaf(wa2, ga2.y - ga2.x, accW);
        accG += ga3.x;  accW = fmaf(wa3, ga3.y - ga3.x, accW);
    }

    // ---- tail: last LDS group (q = 22) ----
    {
        const float4 cl = cs4[csl_base + 22];
        const float4 sl = sy4[csl_base + 22];
        const float4 o4 = of4[of_base + 22];
        const float2* wp = wbase + (22 * 4) * W_;
        {
            float u = fmaf(gX, cl.x, fmaf(ngy, sl.x, o4.x));
            u = fminf(fmaxf(u, 0.0f), 22.999f);
            const float2 g = wp[(int)u];
            accG += g.x;  accW = fmaf(__builtin_amdgcn_fractf(u), g.y - g.x, accW);
        }
        {
            float u = fmaf(gX, cl.y, fmaf(ngy, sl.y, o4.y));
            u = fminf(fmaxf(u, 0.0f), 22.999f);
            const float2 g = wp[W_ + (int)u];
            accG += g.x;  accW = fmaf(__builtin_amdgcn_fractf(u), g.y - g.x, accW);
        }
        {
            float u = fmaf(gX, cl.z, fmaf(ngy, sl.z, o4.z));
            u = fminf(fmaxf(u, 0.0f), 22.999f);
            const float2 g = wp[2 * W_ + (int)u];
            accG += g.x;  accW = fmaf(__builtin_amdgcn_fractf(u), g.y - g.x, accW);
        }
        {
            float u = fmaf(gX, cl.w, fmaf(ngy, sl.w, o4.w));
            u = fminf(fmaxf(u, 0.0f), 22.999f);
            const float2 g = wp[3 * W_ + (int)u];
            accG += g.x;  accW = fmaf(__builtin_amdgcn_fractf(u), g.y - g.x, accW);
        }
    }

    const float part = accG + accW;
    if (team == 1) red[t] = part;
    __syncthreads();
    if (team == 0) {
        const float inside = (fmaf(gX, gX, gy * gy) <= 1.0f) ? 1.0f : 0.0f;
        const float scale  = (float)(M_PI / (2.0 * (double)A_));
        out[(((n * NP_) + p) * PS_ + i) * PS_ + j] =
            (part + red[t]) * inside * scale;
    }
}

extern "C" void kernel_launch(void* const* d_in, const int* in_sizes, int n_in,
                              void* d_out, int out_size, void* d_ws, size_t ws_size,
                              hipStream_t stream) {
    const float* sino  = (const float*)d_in[0];
    const float* theta = (const float*)d_in[1];
    const float* cxs   = (const float*)d_in[2];
    const float* cys   = (const float*)d_in[3];
    float* out = (float*)d_out;

    const int blocks = N_ * NP_ * (PS_ * PS_ / 256);  // 1024
    fbp_kernel<<<dim3(blocks), dim3(512), 0, stream>>>(sino, theta, cxs, cys, out);
}

// Round 9
// 31.188 us; speedup vs baseline: 1.0434x; 1.0434x over previous
//
#include <hip/hip_runtime.h>
#include <math.h>

#define N_  2
#define A_  360
#define M_  512
#define NP_ 32
#define PS_ 64
#define HALF_A 180
#define W_  24            // float2 pairs per window (region span <= 21.3, +interp +slack)

// 512-thread blocks, two 256-thread angle-teams per 16x16 pixel region.
// Windows staged as pairs {s[k], s[k+1]-s[k]} so the divergent gather is ONE
// aligned ds_read_b64. Tables read as uniform float4 broadcasts per 4 angles.
// LDS = 74.5 KB -> 2 blocks/CU (16 waves/CU; per-CU-throughput-bound, enough).
__global__ __launch_bounds__(512) void fbp_kernel(
    const float* __restrict__ sino,   // (N,1,A,M)
    const float* __restrict__ theta,  // (A)
    const float* __restrict__ cxs,    // (NP)
    const float* __restrict__ cys,    // (NP)
    float* __restrict__ out)          // (N,NP,PS,PS)
{
    __shared__ float2 win2[A_ * W_];               // 69120 B: {g0, g1-g0}
    __shared__ alignas(16) float csA[A_];          // 1440 B: cos*half
    __shared__ alignas(16) float syA[A_];          // 1440 B: sin*half
    __shared__ alignas(16) float ofA[A_];          // 1440 B: half - lo
    __shared__ float red[256];                     // 1024 B  => 74464 B total

    const float half = 255.5f;        // (M-1)/2
    const int tid = threadIdx.x;

    const int bid    = blockIdx.x;
    const int region = bid & 15;            // 4x4 regions per 64x64 patch
    const int p      = (bid >> 4) & (NP_ - 1);
    const int n      = bid >> 9;
    const int ri     = (region >> 2) << 4;
    const int rj     = (region &  3) << 4;

    const float cx = cxs[p];
    const float cy = cys[p];

    // Region corner coords (same op sequence as per-pixel => covering bounds)
    const float gX0 = ((float)(ri      - PS_ / 2) + cx) / half - 1.0f;
    const float gX1 = ((float)(ri + 15 - PS_ / 2) + cx) / half - 1.0f;
    const float gy0 = ((float)(rj      - PS_ / 2) + cy) / half - 1.0f;
    const float gy1 = ((float)(rj + 15 - PS_ / 2) + cy) / half - 1.0f;

    // Phase A: per-angle trig + window origin (fused as offs = half - lo)
    if (tid < A_) {
        const float th  = theta[tid];
        const float csx = cosf(th) * half;
        const float csy = sinf(th) * half;
        const float t0  = fmaf(-gy0, csy, half);
        const float t1  = fmaf(-gy1, csy, half);
        const float u00 = fmaf(gX0, csx, t0);
        const float u10 = fmaf(gX1, csx, t0);
        const float u01 = fmaf(gX0, csx, t1);
        const float u11 = fmaf(gX1, csx, t1);
        const float lof = floorf(fminf(fminf(u00, u10), fminf(u01, u11)));
        csA[tid] = csx;
        syA[tid] = csy;
        ofA[tid] = half - lof;        // exact: lof integer, half = 255.5
    }
    __syncthreads();

    // Phase B: stage pair-windows {g0, g1-g0} (coalesced global, linear LDS)
    const float* __restrict__ srow = sino + n * (A_ * M_);
    for (int e = tid; e < A_ * W_; e += 512) {
        const int a  = e / W_;
        const int k  = e - a * W_;
        const int lo = (int)(half - ofA[a]);       // exact recovery
        const int i0 = min(max(lo + k,     0), M_ - 1);
        const int i1 = min(max(lo + k + 1, 0), M_ - 1);
        const float g0 = srow[a * M_ + i0];
        const float g1 = srow[a * M_ + i1];
        win2[e] = make_float2(g0, g1 - g0);
    }
    __syncthreads();

    // Phase C: 180 angles per team, one ds_read_b64 gather per angle
    const int team = tid >> 8;
    const int t    = tid & 255;
    const int i    = ri + (t >> 4);
    const int j    = rj + (t & 15);

    const float gX  = ((float)(i - PS_ / 2) + cx) / half - 1.0f;
    const float gy  = ((float)(j - PS_ / 2) + cy) / half - 1.0f;
    const float ngy = -gy;

    const int gbase = team * (HALF_A / 4);         // float4 group index
    const float4* __restrict__ cs4 = (const float4*)csA;
    const float4* __restrict__ sy4 = (const float4*)syA;
    const float4* __restrict__ of4 = (const float4*)ofA;

    float accG = 0.0f;
    float accW = 0.0f;
    const float2* wp0 = win2 + team * (HALF_A * W_);

    #pragma unroll 3
    for (int g = 0; g < HALF_A / 4; ++g) {
        const float4 c4 = cs4[gbase + g];
        const float4 s4 = sy4[gbase + g];
        const float4 o4 = of4[gbase + g];
        const float2* wp = wp0 + g * (4 * W_);

        {   // sub-iter 0
            float u = fmaf(gX, c4.x, fmaf(ngy, s4.x, o4.x));
            u = fminf(fmaxf(u, 0.0f), 22.999f);
            const float2 gg = wp[(int)u];
            accG += gg.x;  accW = fmaf(__builtin_amdgcn_fractf(u), gg.y, accW);
        }
        {   // sub-iter 1
            float u = fmaf(gX, c4.y, fmaf(ngy, s4.y, o4.y));
            u = fminf(fmaxf(u, 0.0f), 22.999f);
            const float2 gg = wp[W_ + (int)u];
            accG += gg.x;  accW = fmaf(__builtin_amdgcn_fractf(u), gg.y, accW);
        }
        {   // sub-iter 2
            float u = fmaf(gX, c4.z, fmaf(ngy, s4.z, o4.z));
            u = fminf(fmaxf(u, 0.0f), 22.999f);
            const float2 gg = wp[2 * W_ + (int)u];
            accG += gg.x;  accW = fmaf(__builtin_amdgcn_fractf(u), gg.y, accW);
        }
        {   // sub-iter 3
            float u = fmaf(gX, c4.w, fmaf(ngy, s4.w, o4.w));
            u = fminf(fmaxf(u, 0.0f), 22.999f);
            const float2 gg = wp[3 * W_ + (int)u];
            accG += gg.x;  accW = fmaf(__builtin_amdgcn_fractf(u), gg.y, accW);
        }
    }

    const float part = accG + accW;
    if (team == 1) red[t] = part;
    __syncthreads();
    if (team == 0) {
        const float inside = (fmaf(gX, gX, gy * gy) <= 1.0f) ? 1.0f : 0.0f;
        const float scale  = (float)(M_PI / (2.0 * (double)A_));
        out[(((n * NP_) + p) * PS_ + i) * PS_ + j] =
            (part + red[t]) * inside * scale;
    }
}

extern "C" void kernel_launch(void* const* d_in, const int* in_sizes, int n_in,
                              void* d_out, int out_size, void* d_ws, size_t ws_size,
                              hipStream_t stream) {
    const float* sino  = (const float*)d_in[0];
    const float* theta = (const float*)d_in[1];
    const float* cxs   = (const float*)d_in[2];
    const float* cys   = (const float*)d_in[3];
    float* out = (float*)d_out;

    const int blocks = N_ * NP_ * (PS_ * PS_ / 256);  // 1024
    fbp_kernel<<<dim3(blocks), dim3(512), 0, stream>>>(sino, theta, cxs, cys, out);
}